// Round 5
// baseline (314.649 us; speedup 1.0000x reference)
//
#include <hip/hip_runtime.h>
#include <cstdint>
#include <cstddef>

// Problem constants (B=128, S=256, H=128, HEADS=8, STEP=1)
#define BB   128
#define SS   256
#define HH   128
#define NH   8
#define DKK  16

typedef unsigned short u16;
typedef __attribute__((ext_vector_type(8))) short   sh8;    // 8 bf16 = 4 VGPRs (MFMA A/B frag)
typedef __attribute__((ext_vector_type(4))) float   f32x4;  // MFMA C/D frag

__device__ __forceinline__ float sigmoidf_(float x) { return 1.f / (1.f + expf(-x)); }

__device__ __forceinline__ u16 f2bf(float x) {
    union { float f; unsigned int u; } v; v.f = x;
    unsigned int r = (v.u + 0x7fffu + ((v.u >> 16) & 1u)) >> 16;  // RNE (finite inputs)
    return (u16)r;
}
__device__ __forceinline__ float bf2f(u16 u) {
    union { unsigned int u; float f; } v; v.u = ((unsigned int)u) << 16;
    return v.f;
}

// ---------------------------------------------------------------------------
// bf16 MFMA GEMM, 128x128 tile, BK=32, 256 threads = 4 waves, each wave 64x64
// (4x4 grid of 16x16x32 MFMA).  B operands are B^T layout [N][K] bf16.
// Software-pipelined: tile k+1 global loads issue before tile k's frag/MFMA.
// XMODE: 0 = bf16 [M][K] row-major
//        1 = fp32 [M][K] (convert to bf16 while staging)
//        2 = concat along K: bf16 Xa (ld ldx) for k<ksplit, bf16 Xc (ld ldx1) after
// OMODE: 1 = bf16 row-major
//        2 = bf16 TRANSPOSED (Out[col*ldo + row], packed ushort4 per C-quad)
//        3 = fused GRU gate epilogue, LDS-gather (W2 cols gate-interleaved,
//            col=4c+g, g: 0=r 1=i 2=n 3=hn); hnew = h - sig(gi)*(h -
//            tanh(i_n + sig(gr)*h_n)); coalesced ushort4 stores.
// Batch (grid.z): z -> zb=z>>1, zh=z&1; element offsets = zb*s?b + zh*s?h.
// All dims are exact multiples of tile sizes for every call — no bounds checks.
// ---------------------------------------------------------------------------
#define BKk 32
#define PK  40   // LDS K pitch in halves (32 + 8): conflict-free frag reads

template<int XMODE, int OMODE>
__global__ __launch_bounds__(256, 4) void gemm_mfma(
    const void* __restrict__ Xa, const void* __restrict__ Xc, int ldx, int ldx1, int ksplit,
    long long sXb, long long sXh,
    const u16* __restrict__ Bw, int ldb, long long sBb, long long sBh,
    const float* __restrict__ bias,
    void* __restrict__ Out, long long ldo, long long sOb, long long sOh,
    int K, const float* __restrict__ hid)
{
    __shared__ __align__(16) char smem[2 * 128 * PK * 2];  // 20480 B
    u16* As = (u16*)smem;
    u16* Bs = (u16*)(smem + 128 * PK * 2);

    const int t  = threadIdx.x;
    const int bm = blockIdx.x * 128;
    const int bn = blockIdx.y * 128;
    const long long zb = blockIdx.z >> 1, zh = blockIdx.z & 1;

    const u16* Bp = Bw + zb * sBb + zh * sBh;

    const int wave = t >> 6, lane = t & 63;
    const int wr = (wave >> 1) * 64, wc = (wave & 1) * 64;
    const int fm = lane & 15, fq = lane >> 4;

    f32x4 acc[4][4] = {};

    const int r0  = t >> 2, kk0 = (t & 3) * 8;  // bf16 staging: 8 halves (16B), 2 chunks
    const int r1  = t >> 3, kk1 = (t & 7) * 4;  // fp32 staging: 4 floats, 4 chunks

    uint4  pX[2];
    float4 pF[4];
    uint4  pB[2];

    auto load_x = [&](int k0) {
        if (XMODE == 1) {
            const float* Xf = (const float*)Xa + zb * sXb + zh * sXh;
            #pragma unroll
            for (int c = 0; c < 4; c++)
                pF[c] = *(const float4*)(Xf + (long long)(bm + r1 + 32 * c) * ldx + k0 + kk1);
        } else if (XMODE == 2 && k0 >= ksplit) {
            #pragma unroll
            for (int c = 0; c < 2; c++)
                pX[c] = *(const uint4*)((const u16*)Xc +
                        (long long)(bm + r0 + 64 * c) * ldx1 + (k0 - ksplit) + kk0);
        } else {
            #pragma unroll
            for (int c = 0; c < 2; c++)
                pX[c] = *(const uint4*)((const u16*)Xa +
                        (long long)(bm + r0 + 64 * c) * ldx + k0 + kk0);
        }
    };
    auto load_b = [&](int k0) {
        #pragma unroll
        for (int c = 0; c < 2; c++)
            pB[c] = *(const uint4*)(Bp + (long long)(bn + r0 + 64 * c) * ldb + k0 + kk0);
    };

    load_x(0);
    load_b(0);

    for (int k0 = 0; k0 < K; k0 += BKk) {
        // ---- commit prefetched tile to LDS ----
        if (XMODE == 1) {
            #pragma unroll
            for (int c = 0; c < 4; c++) {
                ushort4 w = { f2bf(pF[c].x), f2bf(pF[c].y), f2bf(pF[c].z), f2bf(pF[c].w) };
                *(ushort4*)&As[(r1 + 32 * c) * PK + kk1] = w;
            }
        } else {
            #pragma unroll
            for (int c = 0; c < 2; c++)
                *(uint4*)&As[(r0 + 64 * c) * PK + kk0] = pX[c];
        }
        #pragma unroll
        for (int c = 0; c < 2; c++)
            *(uint4*)&Bs[(r0 + 64 * c) * PK + kk0] = pB[c];
        __syncthreads();

        // ---- issue next-tile loads (hide HBM latency behind frag+MFMA) ----
        if (k0 + BKk < K) { load_x(k0 + BKk); load_b(k0 + BKk); }

        sh8 af[4], bfr[4];
        #pragma unroll
        for (int i = 0; i < 4; i++) af[i]  = *(const sh8*)&As[(wr + i * 16 + fm) * PK + fq * 8];
        #pragma unroll
        for (int j = 0; j < 4; j++) bfr[j] = *(const sh8*)&Bs[(wc + j * 16 + fm) * PK + fq * 8];
        #pragma unroll
        for (int i = 0; i < 4; i++)
            #pragma unroll
            for (int j = 0; j < 4; j++)
                acc[i][j] = __builtin_amdgcn_mfma_f32_16x16x32_bf16(af[i], bfr[j], acc[i][j], 0, 0, 0);
        __syncthreads();
    }

    if (OMODE != 3) {
        // ---- epilogue: C layout col=lane&15, row=(lane>>4)*4+reg ----
        #pragma unroll
        for (int j = 0; j < 4; j++) {
            const int col = bn + wc + j * 16 + fm;
            const float bj = bias ? bias[col] : 0.f;
            #pragma unroll
            for (int i = 0; i < 4; i++) {
                const int row0 = bm + wr + i * 16 + fq * 4;
                if (OMODE == 1) {
                    u16* O = (u16*)Out + zb * sOb + zh * sOh;
                    #pragma unroll
                    for (int r = 0; r < 4; r++)
                        O[(long long)(row0 + r) * ldo + col] = f2bf(acc[i][j][r] + bj);
                } else {  // OMODE == 2
                    u16* O = (u16*)Out + zb * sOb + zh * sOh;
                    ushort4 w = { f2bf(acc[i][j][0] + bj), f2bf(acc[i][j][1] + bj),
                                  f2bf(acc[i][j][2] + bj), f2bf(acc[i][j][3] + bj) };
                    *(ushort4*)&O[(long long)col * ldo + row0] = w;  // 4 consecutive rows
                }
            }
        }
    } else {
        // ---- OMODE == 3: fused GRU epilogue, LDS-gather ----
        float* g4s = (float*)smem;       // [32][132] fp32 = 16896 B (reuses As/Bs)
        const int chbase = bn >> 2;      // global channel base for this block
        const int s_t = t >> 3;          // 0..31 slab row
        const int cq  = t & 7;           // 0..7 channel quad
        u16* O = (u16*)Out;
        const int sbase = (wr ? 16 : 0) + fq * 4;
        #pragma unroll
        for (int i = 0; i < 4; i++) {
            // scatter acc+bias into LDS (rows of both wave halves -> 32 slab rows)
            #pragma unroll
            for (int j = 0; j < 4; j++) {
                const int q = wc + j * 16 + fm;
                const float bj = bias[bn + q];
                #pragma unroll
                for (int r = 0; r < 4; r++)
                    g4s[(sbase + r) * 132 + q] = acc[i][j][r] + bj;
            }
            __syncthreads();
            // gather: 1 row x 4 channels per thread, contiguous b128 reads
            {
                const int grow = bm + i * 16 + (s_t < 16 ? s_t : s_t + 48);
                const float4 hv = *(const float4*)&hid[(long long)grow * HH + chbase + 4 * cq];
                const float hvv[4] = { hv.x, hv.y, hv.z, hv.w };
                ushort4 w;
                u16* wp = (u16*)&w;
                #pragma unroll
                for (int m = 0; m < 4; m++) {
                    f32x4 gv = *(const f32x4*)&g4s[s_t * 132 + 16 * cq + 4 * m];
                    float rg = sigmoidf_(gv[0]);
                    float ig = sigmoidf_(gv[1]);
                    float ng = tanhf(gv[2] + rg * gv[3]);
                    wp[m] = f2bf(hvv[m] - ig * (hvv[m] - ng));
                }
                *(ushort4*)&O[(long long)grow * ldo + chbase + 4 * cq] = w;
            }
            __syncthreads();
        }
    }
}

// ---------------------------------------------------------------------------
// Weight prep + hidden cast (one kernel, grid 4096x256).
//   h_bf = bf16(hidden)  (1048576 float4s)
//   W2bf [512x384], GATE-INTERLEAVED rows: np = 4c+g, g: 0=r 1=i 2=n 3=hn.
//   bias2[np] = gate bias + fold of (b_iah|b_oah) through w_ih (linear terms).
//   Wcat [256x128] = [W_ein; W_eout], biascat = [b_ein|b_eout]
//   Wq12 [256x128] = [W_q1; W_q2],    biasq12 = [b_q1|b_q2]
// ---------------------------------------------------------------------------
__global__ __launch_bounds__(256) void k_prepw(
    const float* __restrict__ hidden, u16* __restrict__ h_bf,
    const float* __restrict__ w_ih, const float* __restrict__ w_hh,
    const float* __restrict__ b_ih, const float* __restrict__ b_hh,
    const float* __restrict__ b_iah, const float* __restrict__ b_oah,
    const float* __restrict__ W_ein, const float* __restrict__ b_ein,
    const float* __restrict__ W_eout, const float* __restrict__ b_eout,
    const float* __restrict__ W_q1, const float* __restrict__ b_q1,
    const float* __restrict__ W_q2, const float* __restrict__ b_q2,
    u16* __restrict__ W2bf, float* __restrict__ bias2,
    u16* __restrict__ Wcat, float* __restrict__ biascat,
    u16* __restrict__ Wq12, float* __restrict__ biasq12)
{
    int idx = blockIdx.x * 256 + threadIdx.x;  // 0 .. 1048575
    {   // hidden -> bf16, 4 elems/thread
        float4 v = ((const float4*)hidden)[idx];
        ushort4 w = { f2bf(v.x), f2bf(v.y), f2bf(v.z), f2bf(v.w) };
        ((ushort4*)h_bf)[idx] = w;
    }
    if (idx < 512 * 384) {
        int np = idx / 384, kk = idx % 384;
        int c = np >> 2, g = np & 3;
        float v;
        if (g < 2)       v = (kk < 256) ? w_ih[(g * 128 + c) * 256 + kk]
                                        : w_hh[(g * 128 + c) * 128 + kk - 256];
        else if (g == 2) v = (kk < 256) ? w_ih[(256 + c) * 256 + kk] : 0.f;
        else             v = (kk < 256) ? 0.f : w_hh[(256 + c) * 128 + kk - 256];
        W2bf[idx] = f2bf(v);
    }
    if (idx < 256 * 128) {
        int n = idx >> 7, k = idx & 127;
        Wcat[idx] = f2bf(n < 128 ? W_ein[n * 128 + k] : W_eout[(n - 128) * 128 + k]);
        Wq12[idx] = f2bf(n < 128 ? W_q1[n * 128 + k]  : W_q2[(n - 128) * 128 + k]);
    }
    if (idx < 512) {
        int np = idx, c = np >> 2, g = np & 3;
        float s;
        if (g < 2)       s = b_ih[g * 128 + c] + b_hh[g * 128 + c];
        else if (g == 2) s = b_ih[256 + c];
        else             s = b_hh[256 + c];
        if (g < 3) {
            int n = (g < 2) ? g * 128 + c : 256 + c;
            for (int k = 0; k < 128; k++)
                s += w_ih[n * 256 + k] * b_iah[k] + w_ih[n * 256 + 128 + k] * b_oah[k];
        }
        bias2[np] = s;
    }
    if (idx < 256) {
        biascat[idx] = idx < 128 ? b_ein[idx] : b_eout[idx - 128];
        biasq12[idx] = idx < 128 ? b_q1[idx]  : b_q2[idx - 128];
    }
}

// ---------------------------------------------------------------------------
// Fused attention tail, one block per batch b (256 threads):
// mask-sum -> last idx -> q0 -> sigmoid scores -> softmax_j -> softmax_h ->
// weighted q2 readout, out[b] scaled by nvalid.  q12 is bf16 [32768][256]
// (cols 0:128 = q1, 128:256 = q2).
// ---------------------------------------------------------------------------
__global__ __launch_bounds__(256) void k_tail(
    const u16* __restrict__ hnew_bf, const int* __restrict__ mask,
    const u16* __restrict__ q12, const float* __restrict__ Wq0,
    const float* __restrict__ bq0, float* __restrict__ out)
{
    const int b = blockIdx.x, t = threadIdx.x;
    __shared__ float red[256];
    __shared__ float hs[HH];
    __shared__ float q0s[HH];
    __shared__ float p_s[NH][SS];
    __shared__ float w_s[NH][SS];
    __shared__ int s_nv;

    // ---- mask sum / last index ----
    red[t] = (float)mask[b * SS + t];
    __syncthreads();
    for (int off = 128; off > 0; off >>= 1) {
        if (t < off) red[t] += red[t + off];
        __syncthreads();
    }
    if (t == 0) s_nv = (int)red[0];
    __syncthreads();
    const int nv = s_nv;
    const int last = (nv - 1) & (SS - 1);

    if (t < HH) hs[t] = bf2f(hnew_bf[((size_t)b * SS + last) * HH + t]);
    __syncthreads();

    // ---- q0 = h_last @ Wq0^T + bq0 (split K over two thread halves) ----
    {
        const int n = t & 127, kh = t >> 7;
        const float* w = Wq0 + (size_t)n * HH + kh * 64;
        float s = 0.f;
        #pragma unroll 16
        for (int k = 0; k < 64; k++) s += hs[kh * 64 + k] * w[k];
        red[t] = s;
    }
    __syncthreads();
    if (t < HH) q0s[t] = red[t] + red[t + 128] + bq0[t];
    __syncthreads();

    // ---- scores: p_s[h][j] = sigmoid(q0[h] . q1[j,h]) ----
    {
        const u16* q1r = q12 + ((size_t)b * SS + t) * 256;
        #pragma unroll
        for (int h = 0; h < NH; h++) {
            float s = 0.f;
            #pragma unroll
            for (int d = 0; d < DKK; d++) s += q0s[h * DKK + d] * bf2f(q1r[h * DKK + d]);
            p_s[h][t] = sigmoidf_(s);
        }
    }
    __syncthreads();

    // ---- softmax over j per head: 32 threads/head, 8 values each ----
    {
        const int h = t >> 5, l = t & 31;
        float v[8], m = -1e30f;
        #pragma unroll
        for (int u = 0; u < 8; u++) { v[u] = p_s[h][l * 8 + u]; m = fmaxf(m, v[u]); }
        #pragma unroll
        for (int msk = 1; msk < 32; msk <<= 1) m = fmaxf(m, __shfl_xor(m, msk, 32));
        float sum = 0.f;
        #pragma unroll
        for (int u = 0; u < 8; u++) { v[u] = expf(v[u] - m); sum += v[u]; }
        #pragma unroll
        for (int msk = 1; msk < 32; msk <<= 1) sum += __shfl_xor(sum, msk, 32);
        const float inv = 1.f / sum;
        #pragma unroll
        for (int u = 0; u < 8; u++) p_s[h][l * 8 + u] = v[u] * inv;
    }
    __syncthreads();

    // ---- head softmax per j ----
    {
        float e[NH], den = 0.f;
        #pragma unroll
        for (int h = 0; h < NH; h++) { e[h] = expf(2.f * p_s[h][t]); den += e[h]; }
        const float inv = 1.f / den;
        #pragma unroll
        for (int h = 0; h < NH; h++) w_s[h][t] = e[h] * inv;
    }
    __syncthreads();

    // ---- readout: out[b,col] = nv * sum_j w[h(col)][j] * q2[j,col] ----
    {
        const int col = t & 127, jh = t >> 7;
        const int h = col >> 4;
        const u16* q2b = q12 + (size_t)b * SS * 256 + 128 + col;
        float acc = 0.f;
        for (int j = jh * 128; j < jh * 128 + 128; j++)
            acc += w_s[h][j] * bf2f(q2b[(size_t)j * 256]);
        red[t] = acc;
    }
    __syncthreads();
    if (t < HH) out[(size_t)b * HH + t] = (red[t] + red[t + 128]) * (float)nv;
}

// ---------------------------------------------------------------------------
extern "C" void kernel_launch(void* const* d_in, const int* in_sizes, int n_in,
                              void* d_out, int out_size, void* d_ws, size_t ws_size,
                              hipStream_t stream)
{
    const float* A      = (const float*)d_in[0];
    const float* hidden = (const float*)d_in[1];
    const int*   mask   = (const int*)d_in[2];
    const float* w_ih   = (const float*)d_in[3];
    const float* w_hh   = (const float*)d_in[4];
    const float* b_ih   = (const float*)d_in[5];
    const float* b_hh   = (const float*)d_in[6];
    const float* b_iah  = (const float*)d_in[7];
    const float* b_oah  = (const float*)d_in[8];
    const float* W_ein  = (const float*)d_in[9];
    const float* b_ein  = (const float*)d_in[10];
    const float* W_eout = (const float*)d_in[11];
    const float* b_eout = (const float*)d_in[12];
    const float* W_q0   = (const float*)d_in[13];
    const float* b_q0   = (const float*)d_in[14];
    const float* W_q1   = (const float*)d_in[15];
    const float* b_q1   = (const float*)d_in[16];
    const float* W_q2   = (const float*)d_in[17];
    const float* b_q2   = (const float*)d_in[18];
    float* out = (float*)d_out;
    char* ws = (char*)d_ws;

    // --- workspace layout (bytes) ---
    u16*   Et      = (u16*)(ws + 0);             // [256][32768] bf16 (E transposed)
    u16*   Mbuf    = (u16*)(ws + 16777216);      // [32768][256] bf16 (msg_in|msg_out)
    u16*   q12bf   = (u16*)(ws + 0);             // [32768][256] bf16 — aliases Et (dead)
    u16*   hnew_bf = (u16*)(ws + 33554432);      // [32768][128] bf16
    u16*   h_bf    = (u16*)(ws + 41943040);      // [32768][128] bf16
    u16*   W2bf    = (u16*)(ws + 50331648);      // [512][384]
    u16*   Wcat    = (u16*)(ws + 50724864);      // [256][128]
    u16*   Wq12    = (u16*)(ws + 50790400);      // [256][128]
    float* bias2   = (float*)(ws + 50855936);    // [512]
    float* biascat = (float*)(ws + 50857984);    // [256]
    float* biasq12 = (float*)(ws + 50859008);    // [256]

    // 1. weight prep + hidden cast
    k_prepw<<<4096, 256, 0, stream>>>(hidden, h_bf,
                                      w_ih, w_hh, b_ih, b_hh, b_iah, b_oah,
                                      W_ein, b_ein, W_eout, b_eout,
                                      W_q1, b_q1, W_q2, b_q2,
                                      W2bf, bias2, Wcat, biascat, Wq12, biasq12);

    // 2. E = h_bf @ [W_ein;W_eout]^T + bias, stored TRANSPOSED (Et[c][r])
    gemm_mfma<0, 2><<<dim3(256, 2, 1), 256, 0, stream>>>(
        h_bf, nullptr, HH, 0, 0, 0, 0,
        Wcat, HH, 0, 0, biascat,
        Et, 32768, 0, 0, HH, nullptr);

    // 3. msg: per (b,half): A-half[b] (fp32, ld 512) @ Et-slice^T -> Mbuf bf16
    gemm_mfma<1, 1><<<dim3(2, 1, 256), 256, 0, stream>>>(
        A, nullptr, 512, 0, 0, 131072LL, 256LL,
        Et, 32768, 256LL, 128LL * 32768LL, nullptr,
        Mbuf, 256, 65536LL, 128LL, SS, nullptr);

    // 4. gates = [Mbuf | h_bf] @ W2bf^T + bias2, fused GRU epilogue
    //    (LDS-gather) -> hnew bf16 directly
    gemm_mfma<2, 3><<<dim3(256, 4, 1), 256, 0, stream>>>(
        Mbuf, h_bf, 256, HH, 256, 0, 0,
        W2bf, 384, 0, 0, bias2,
        hnew_bf, HH, 0, 0, 384, hidden);

    // 5. q12 = hnew @ [W_q1;W_q2]^T + bias (bf16 out, aliases Et region)
    gemm_mfma<0, 1><<<dim3(256, 2, 1), 256, 0, stream>>>(
        hnew_bf, nullptr, HH, 0, 0, 0, 0,
        Wq12, HH, 0, 0, biasq12,
        q12bf, 256, 0, 0, HH, nullptr);

    // 6. fused attention tail (mask, q0, scores, softmaxes, readout)
    k_tail<<<BB, 256, 0, stream>>>(hnew_bf, mask, q12bf, W_q0, b_q0, out);
}

// Round 6
// 249.720 us; speedup vs baseline: 1.2600x; 1.2600x over previous
//
#include <hip/hip_runtime.h>
#include <cstdint>
#include <cstddef>

// Problem constants (B=128, S=256, H=128, HEADS=8, STEP=1)
#define BB   128
#define SS   256
#define HH   128
#define NH   8
#define DKK  16

typedef unsigned short u16;
typedef __attribute__((ext_vector_type(8))) short   sh8;    // 8 bf16 = 4 VGPRs (MFMA A/B frag)
typedef __attribute__((ext_vector_type(4))) float   f32x4;  // MFMA C/D frag

__device__ __forceinline__ float sigmoidf_(float x) { return 1.f / (1.f + expf(-x)); }

__device__ __forceinline__ u16 f2bf(float x) {
    union { float f; unsigned int u; } v; v.f = x;
    unsigned int r = (v.u + 0x7fffu + ((v.u >> 16) & 1u)) >> 16;  // RNE (finite inputs)
    return (u16)r;
}
__device__ __forceinline__ float bf2f(u16 u) {
    union { unsigned int u; float f; } v; v.u = ((unsigned int)u) << 16;
    return v.f;
}

// ---------------------------------------------------------------------------
// bf16 MFMA GEMM, 128x128 tile, BK=32, 256 threads = 4 waves, each wave 64x64
// (4x4 grid of 16x16x32 MFMA).  B operands are B^T layout [N][K] bf16.
// Software-pipelined via NAMED register variables (px0/px1/pf0..3/pb0/pb1) and
// straight-line macro loads — NO lambdas/arrays (round-5 lambda capture left
// the prefetch in allocas -> 156 MB scratch traffic, 45->74 us regression).
// XMODE: 0 = bf16 [M][K] row-major
//        1 = fp32 [M][K] (convert to bf16 while staging)
//        2 = concat along K: bf16 Xa (ld ldx) for k<ksplit, bf16 Xc (ld ldx1) after
// OMODE: 1 = bf16 row-major
//        2 = bf16 TRANSPOSED (Out[col*ldo + row], packed ushort4 per C-quad)
//        3 = fused GRU gate epilogue, LDS-gather (W2 cols gate-interleaved,
//            col=4c+g, g: 0=r 1=i 2=n 3=hn); hnew = h - sig(gi)*(h -
//            tanh(i_n + sig(gr)*h_n)); h read from bf16 hid; coalesced stores.
// Batch (grid.z): z -> zb=z>>1, zh=z&1; element offsets = zb*s?b + zh*s?h.
// All dims are exact multiples of tile sizes for every call — no bounds checks.
// ---------------------------------------------------------------------------
#define BKk 32
#define PK  40   // LDS K pitch in halves (32 + 8): conflict-free frag reads

template<int XMODE, int OMODE>
__global__ __launch_bounds__(256) void gemm_mfma(
    const void* __restrict__ Xa, const void* __restrict__ Xc, int ldx, int ldx1, int ksplit,
    long long sXb, long long sXh,
    const u16* __restrict__ Bw, int ldb, long long sBb, long long sBh,
    const float* __restrict__ bias,
    void* __restrict__ Out, long long ldo, long long sOb, long long sOh,
    int K, const u16* __restrict__ hid)
{
    __shared__ __align__(16) char smem[2 * 128 * PK * 2];  // 20480 B
    u16* As = (u16*)smem;
    u16* Bs = (u16*)(smem + 128 * PK * 2);

    const int t  = threadIdx.x;
    const int bm = blockIdx.x * 128;
    const int bn = blockIdx.y * 128;
    const long long zb = blockIdx.z >> 1, zh = blockIdx.z & 1;

    const u16* Bp = Bw + zb * sBb + zh * sBh;

    const int wave = t >> 6, lane = t & 63;
    const int wr = (wave >> 1) * 64, wc = (wave & 1) * 64;
    const int fm = lane & 15, fq = lane >> 4;

    f32x4 acc[4][4] = {};

    const int r0  = t >> 2, kk0 = (t & 3) * 8;  // bf16 staging: 8 halves (16B), 2 chunks
    const int r1  = t >> 3, kk1 = (t & 7) * 4;  // fp32 staging: 4 floats, 4 chunks

    // prefetch registers — named scalars only (keep them out of scratch!)
    uint4  px0, px1, pb0, pb1;
    float4 pf0, pf1, pf2, pf3;

#define LOADX(K0)                                                                    \
    if (XMODE == 1) {                                                                \
        const float* Xf_ = (const float*)Xa + zb * sXb + zh * sXh;                   \
        const float* xp_ = Xf_ + (long long)(bm + r1) * ldx + (K0) + kk1;            \
        pf0 = *(const float4*)(xp_);                                                 \
        pf1 = *(const float4*)(xp_ + 32LL * ldx);                                    \
        pf2 = *(const float4*)(xp_ + 64LL * ldx);                                    \
        pf3 = *(const float4*)(xp_ + 96LL * ldx);                                    \
    } else if (XMODE == 2 && (K0) >= ksplit) {                                       \
        const u16* xp_ = (const u16*)Xc + (long long)(bm + r0) * ldx1                \
                         + ((K0) - ksplit) + kk0;                                    \
        px0 = *(const uint4*)(xp_);                                                  \
        px1 = *(const uint4*)(xp_ + 64LL * ldx1);                                    \
    } else {                                                                         \
        const u16* xp_ = (const u16*)Xa + (long long)(bm + r0) * ldx + (K0) + kk0;   \
        px0 = *(const uint4*)(xp_);                                                  \
        px1 = *(const uint4*)(xp_ + 64LL * ldx);                                     \
    }

#define LOADB(K0)                                                                    \
    {                                                                                \
        const u16* bp_ = Bp + (long long)(bn + r0) * ldb + (K0) + kk0;               \
        pb0 = *(const uint4*)(bp_);                                                  \
        pb1 = *(const uint4*)(bp_ + 64LL * ldb);                                     \
    }

    LOADX(0)
    LOADB(0)

    for (int k0 = 0; k0 < K; k0 += BKk) {
        // ---- commit prefetched tile to LDS ----
        if (XMODE == 1) {
            ushort4 w0 = { f2bf(pf0.x), f2bf(pf0.y), f2bf(pf0.z), f2bf(pf0.w) };
            ushort4 w1 = { f2bf(pf1.x), f2bf(pf1.y), f2bf(pf1.z), f2bf(pf1.w) };
            ushort4 w2 = { f2bf(pf2.x), f2bf(pf2.y), f2bf(pf2.z), f2bf(pf2.w) };
            ushort4 w3 = { f2bf(pf3.x), f2bf(pf3.y), f2bf(pf3.z), f2bf(pf3.w) };
            *(ushort4*)&As[(r1     ) * PK + kk1] = w0;
            *(ushort4*)&As[(r1 + 32) * PK + kk1] = w1;
            *(ushort4*)&As[(r1 + 64) * PK + kk1] = w2;
            *(ushort4*)&As[(r1 + 96) * PK + kk1] = w3;
        } else {
            *(uint4*)&As[(r0     ) * PK + kk0] = px0;
            *(uint4*)&As[(r0 + 64) * PK + kk0] = px1;
        }
        *(uint4*)&Bs[(r0     ) * PK + kk0] = pb0;
        *(uint4*)&Bs[(r0 + 64) * PK + kk0] = pb1;
        __syncthreads();

        // ---- issue next-tile loads (hide HBM latency behind frag+MFMA) ----
        if (k0 + BKk < K) {
            LOADX(k0 + BKk)
            LOADB(k0 + BKk)
        }

        sh8 af[4], bfr[4];
        #pragma unroll
        for (int i = 0; i < 4; i++) af[i]  = *(const sh8*)&As[(wr + i * 16 + fm) * PK + fq * 8];
        #pragma unroll
        for (int j = 0; j < 4; j++) bfr[j] = *(const sh8*)&Bs[(wc + j * 16 + fm) * PK + fq * 8];
        #pragma unroll
        for (int i = 0; i < 4; i++)
            #pragma unroll
            for (int j = 0; j < 4; j++)
                acc[i][j] = __builtin_amdgcn_mfma_f32_16x16x32_bf16(af[i], bfr[j], acc[i][j], 0, 0, 0);
        __syncthreads();
    }
#undef LOADX
#undef LOADB

    if (OMODE != 3) {
        // ---- epilogue: C layout col=lane&15, row=(lane>>4)*4+reg ----
        #pragma unroll
        for (int j = 0; j < 4; j++) {
            const int col = bn + wc + j * 16 + fm;
            const float bj = bias ? bias[col] : 0.f;
            #pragma unroll
            for (int i = 0; i < 4; i++) {
                const int row0 = bm + wr + i * 16 + fq * 4;
                if (OMODE == 1) {
                    u16* O = (u16*)Out + zb * sOb + zh * sOh;
                    #pragma unroll
                    for (int r = 0; r < 4; r++)
                        O[(long long)(row0 + r) * ldo + col] = f2bf(acc[i][j][r] + bj);
                } else {  // OMODE == 2
                    u16* O = (u16*)Out + zb * sOb + zh * sOh;
                    ushort4 w = { f2bf(acc[i][j][0] + bj), f2bf(acc[i][j][1] + bj),
                                  f2bf(acc[i][j][2] + bj), f2bf(acc[i][j][3] + bj) };
                    *(ushort4*)&O[(long long)col * ldo + row0] = w;  // 4 consecutive rows
                }
            }
        }
    } else {
        // ---- OMODE == 3: fused GRU epilogue, LDS-gather ----
        float* g4s = (float*)smem;       // [32][132] fp32 = 16896 B (reuses As/Bs)
        const int chbase = bn >> 2;      // global channel base for this block
        const int s_t = t >> 3;          // 0..31 slab row
        const int cq  = t & 7;           // 0..7 channel quad
        u16* O = (u16*)Out;
        const int sbase = (wr ? 16 : 0) + fq * 4;
        #pragma unroll
        for (int i = 0; i < 4; i++) {
            // scatter acc+bias into LDS (rows of both wave halves -> 32 slab rows)
            #pragma unroll
            for (int j = 0; j < 4; j++) {
                const int q = wc + j * 16 + fm;
                const float bj = bias[bn + q];
                #pragma unroll
                for (int r = 0; r < 4; r++)
                    g4s[(sbase + r) * 132 + q] = acc[i][j][r] + bj;
            }
            __syncthreads();
            // gather: 1 row x 4 channels per thread, contiguous b128 reads
            {
                const int grow = bm + i * 16 + (s_t < 16 ? s_t : s_t + 48);
                const ushort4 hv = *(const ushort4*)&hid[(long long)grow * HH + chbase + 4 * cq];
                const float hvv[4] = { bf2f(hv.x), bf2f(hv.y), bf2f(hv.z), bf2f(hv.w) };
                ushort4 w;
                u16* wp = (u16*)&w;
                #pragma unroll
                for (int m = 0; m < 4; m++) {
                    f32x4 gv = *(const f32x4*)&g4s[s_t * 132 + 16 * cq + 4 * m];
                    float rg = sigmoidf_(gv[0]);
                    float ig = sigmoidf_(gv[1]);
                    float ng = tanhf(gv[2] + rg * gv[3]);
                    wp[m] = f2bf(hvv[m] - ig * (hvv[m] - ng));
                }
                *(ushort4*)&O[(long long)grow * ldo + chbase + 4 * cq] = w;
            }
            __syncthreads();
        }
    }
}

// ---------------------------------------------------------------------------
// Weight prep + hidden cast (one kernel, grid 4096x256).
//   h_bf = bf16(hidden)  (1048576 float4s)
//   W2bf [512x384], GATE-INTERLEAVED rows: np = 4c+g, g: 0=r 1=i 2=n 3=hn.
//   bias2[np] = gate bias + fold of (b_iah|b_oah) through w_ih (linear terms).
//   Wcat [256x128] = [W_ein; W_eout], biascat = [b_ein|b_eout]
//   Wq12 [256x128] = [W_q1; W_q2],    biasq12 = [b_q1|b_q2]
// ---------------------------------------------------------------------------
__global__ __launch_bounds__(256) void k_prepw(
    const float* __restrict__ hidden, u16* __restrict__ h_bf,
    const float* __restrict__ w_ih, const float* __restrict__ w_hh,
    const float* __restrict__ b_ih, const float* __restrict__ b_hh,
    const float* __restrict__ b_iah, const float* __restrict__ b_oah,
    const float* __restrict__ W_ein, const float* __restrict__ b_ein,
    const float* __restrict__ W_eout, const float* __restrict__ b_eout,
    const float* __restrict__ W_q1, const float* __restrict__ b_q1,
    const float* __restrict__ W_q2, const float* __restrict__ b_q2,
    u16* __restrict__ W2bf, float* __restrict__ bias2,
    u16* __restrict__ Wcat, float* __restrict__ biascat,
    u16* __restrict__ Wq12, float* __restrict__ biasq12)
{
    int idx = blockIdx.x * 256 + threadIdx.x;  // 0 .. 1048575
    {   // hidden -> bf16, 4 elems/thread
        float4 v = ((const float4*)hidden)[idx];
        ushort4 w = { f2bf(v.x), f2bf(v.y), f2bf(v.z), f2bf(v.w) };
        ((ushort4*)h_bf)[idx] = w;
    }
    if (idx < 512 * 384) {
        int np = idx / 384, kk = idx % 384;
        int c = np >> 2, g = np & 3;
        float v;
        if (g < 2)       v = (kk < 256) ? w_ih[(g * 128 + c) * 256 + kk]
                                        : w_hh[(g * 128 + c) * 128 + kk - 256];
        else if (g == 2) v = (kk < 256) ? w_ih[(256 + c) * 256 + kk] : 0.f;
        else             v = (kk < 256) ? 0.f : w_hh[(256 + c) * 128 + kk - 256];
        W2bf[idx] = f2bf(v);
    }
    if (idx < 256 * 128) {
        int n = idx >> 7, k = idx & 127;
        Wcat[idx] = f2bf(n < 128 ? W_ein[n * 128 + k] : W_eout[(n - 128) * 128 + k]);
        Wq12[idx] = f2bf(n < 128 ? W_q1[n * 128 + k]  : W_q2[(n - 128) * 128 + k]);
    }
    if (idx < 512) {
        int np = idx, c = np >> 2, g = np & 3;
        float s;
        if (g < 2)       s = b_ih[g * 128 + c] + b_hh[g * 128 + c];
        else if (g == 2) s = b_ih[256 + c];
        else             s = b_hh[256 + c];
        if (g < 3) {
            int n = (g < 2) ? g * 128 + c : 256 + c;
            for (int k = 0; k < 128; k++)
                s += w_ih[n * 256 + k] * b_iah[k] + w_ih[n * 256 + 128 + k] * b_oah[k];
        }
        bias2[np] = s;
    }
    if (idx < 256) {
        biascat[idx] = idx < 128 ? b_ein[idx] : b_eout[idx - 128];
        biasq12[idx] = idx < 128 ? b_q1[idx]  : b_q2[idx - 128];
    }
}

// ---------------------------------------------------------------------------
// Fused attention tail, one block per batch b (256 threads):
// mask-sum -> last idx -> q0 -> sigmoid scores -> softmax_j -> softmax_h ->
// weighted q2 readout, out[b] scaled by nvalid.  q12 is bf16 [32768][256]
// (cols 0:128 = q1, 128:256 = q2).
// ---------------------------------------------------------------------------
__global__ __launch_bounds__(256) void k_tail(
    const u16* __restrict__ hnew_bf, const int* __restrict__ mask,
    const u16* __restrict__ q12, const float* __restrict__ Wq0,
    const float* __restrict__ bq0, float* __restrict__ out)
{
    const int b = blockIdx.x, t = threadIdx.x;
    __shared__ float red[256];
    __shared__ float hs[HH];
    __shared__ float q0s[HH];
    __shared__ float p_s[NH][SS];
    __shared__ float w_s[NH][SS];
    __shared__ int s_nv;

    // ---- mask sum / last index ----
    red[t] = (float)mask[b * SS + t];
    __syncthreads();
    for (int off = 128; off > 0; off >>= 1) {
        if (t < off) red[t] += red[t + off];
        __syncthreads();
    }
    if (t == 0) s_nv = (int)red[0];
    __syncthreads();
    const int nv = s_nv;
    const int last = (nv - 1) & (SS - 1);

    if (t < HH) hs[t] = bf2f(hnew_bf[((size_t)b * SS + last) * HH + t]);
    __syncthreads();

    // ---- q0 = h_last @ Wq0^T + bq0 (split K over two thread halves) ----
    {
        const int n = t & 127, kh = t >> 7;
        const float* w = Wq0 + (size_t)n * HH + kh * 64;
        float s = 0.f;
        #pragma unroll 16
        for (int k = 0; k < 64; k++) s += hs[kh * 64 + k] * w[k];
        red[t] = s;
    }
    __syncthreads();
    if (t < HH) q0s[t] = red[t] + red[t + 128] + bq0[t];
    __syncthreads();

    // ---- scores: p_s[h][j] = sigmoid(q0[h] . q1[j,h]) ----
    {
        const u16* q1r = q12 + ((size_t)b * SS + t) * 256;
        #pragma unroll
        for (int h = 0; h < NH; h++) {
            float s = 0.f;
            #pragma unroll
            for (int d = 0; d < DKK; d++) s += q0s[h * DKK + d] * bf2f(q1r[h * DKK + d]);
            p_s[h][t] = sigmoidf_(s);
        }
    }
    __syncthreads();

    // ---- softmax over j per head: 32 threads/head, 8 values each ----
    {
        const int h = t >> 5, l = t & 31;
        float v[8], m = -1e30f;
        #pragma unroll
        for (int u = 0; u < 8; u++) { v[u] = p_s[h][l * 8 + u]; m = fmaxf(m, v[u]); }
        #pragma unroll
        for (int msk = 1; msk < 32; msk <<= 1) m = fmaxf(m, __shfl_xor(m, msk, 32));
        float sum = 0.f;
        #pragma unroll
        for (int u = 0; u < 8; u++) { v[u] = expf(v[u] - m); sum += v[u]; }
        #pragma unroll
        for (int msk = 1; msk < 32; msk <<= 1) sum += __shfl_xor(sum, msk, 32);
        const float inv = 1.f / sum;
        #pragma unroll
        for (int u = 0; u < 8; u++) p_s[h][l * 8 + u] = v[u] * inv;
    }
    __syncthreads();

    // ---- head softmax per j ----
    {
        float e[NH], den = 0.f;
        #pragma unroll
        for (int h = 0; h < NH; h++) { e[h] = expf(2.f * p_s[h][t]); den += e[h]; }
        const float inv = 1.f / den;
        #pragma unroll
        for (int h = 0; h < NH; h++) w_s[h][t] = e[h] * inv;
    }
    __syncthreads();

    // ---- readout: out[b,col] = nv * sum_j w[h(col)][j] * q2[j,col] ----
    {
        const int col = t & 127, jh = t >> 7;
        const int h = col >> 4;
        const u16* q2b = q12 + (size_t)b * SS * 256 + 128 + col;
        float acc = 0.f;
        for (int j = jh * 128; j < jh * 128 + 128; j++)
            acc += w_s[h][j] * bf2f(q2b[(size_t)j * 256]);
        red[t] = acc;
    }
    __syncthreads();
    if (t < HH) out[(size_t)b * HH + t] = (red[t] + red[t + 128]) * (float)nv;
}

// ---------------------------------------------------------------------------
extern "C" void kernel_launch(void* const* d_in, const int* in_sizes, int n_in,
                              void* d_out, int out_size, void* d_ws, size_t ws_size,
                              hipStream_t stream)
{
    const float* A      = (const float*)d_in[0];
    const float* hidden = (const float*)d_in[1];
    const int*   mask   = (const int*)d_in[2];
    const float* w_ih   = (const float*)d_in[3];
    const float* w_hh   = (const float*)d_in[4];
    const float* b_ih   = (const float*)d_in[5];
    const float* b_hh   = (const float*)d_in[6];
    const float* b_iah  = (const float*)d_in[7];
    const float* b_oah  = (const float*)d_in[8];
    const float* W_ein  = (const float*)d_in[9];
    const float* b_ein  = (const float*)d_in[10];
    const float* W_eout = (const float*)d_in[11];
    const float* b_eout = (const float*)d_in[12];
    const float* W_q0   = (const float*)d_in[13];
    const float* b_q0   = (const float*)d_in[14];
    const float* W_q1   = (const float*)d_in[15];
    const float* b_q1   = (const float*)d_in[16];
    const float* W_q2   = (const float*)d_in[17];
    const float* b_q2   = (const float*)d_in[18];
    float* out = (float*)d_out;
    char* ws = (char*)d_ws;

    // --- workspace layout (bytes) ---
    u16*   Et      = (u16*)(ws + 0);             // [256][32768] bf16 (E transposed)
    u16*   Mbuf    = (u16*)(ws + 16777216);      // [32768][256] bf16 (msg_in|msg_out)
    u16*   q12bf   = (u16*)(ws + 0);             // [32768][256] bf16 — aliases Et (dead)
    u16*   hnew_bf = (u16*)(ws + 33554432);      // [32768][128] bf16
    u16*   h_bf    = (u16*)(ws + 41943040);      // [32768][128] bf16
    u16*   W2bf    = (u16*)(ws + 50331648);      // [512][384]
    u16*   Wcat    = (u16*)(ws + 50724864);      // [256][128]
    u16*   Wq12    = (u16*)(ws + 50790400);      // [256][128]
    float* bias2   = (float*)(ws + 50855936);    // [512]
    float* biascat = (float*)(ws + 50857984);    // [256]
    float* biasq12 = (float*)(ws + 50859008);    // [256]

    // 1. weight prep + hidden cast
    k_prepw<<<4096, 256, 0, stream>>>(hidden, h_bf,
                                      w_ih, w_hh, b_ih, b_hh, b_iah, b_oah,
                                      W_ein, b_ein, W_eout, b_eout,
                                      W_q1, b_q1, W_q2, b_q2,
                                      W2bf, bias2, Wcat, biascat, Wq12, biasq12);

    // 2. E = h_bf @ [W_ein;W_eout]^T + bias, stored TRANSPOSED (Et[c][r])
    gemm_mfma<0, 2><<<dim3(256, 2, 1), 256, 0, stream>>>(
        h_bf, nullptr, HH, 0, 0, 0, 0,
        Wcat, HH, 0, 0, biascat,
        Et, 32768, 0, 0, HH, nullptr);

    // 3. msg: per (b,half): A-half[b] (fp32, ld 512) @ Et-slice^T -> Mbuf bf16
    gemm_mfma<1, 1><<<dim3(2, 1, 256), 256, 0, stream>>>(
        A, nullptr, 512, 0, 0, 131072LL, 256LL,
        Et, 32768, 256LL, 128LL * 32768LL, nullptr,
        Mbuf, 256, 65536LL, 128LL, SS, nullptr);

    // 4. gates = [Mbuf | h_bf] @ W2bf^T + bias2, fused GRU epilogue
    //    (LDS-gather) -> hnew bf16 directly
    gemm_mfma<2, 3><<<dim3(256, 4, 1), 256, 0, stream>>>(
        Mbuf, h_bf, 256, HH, 256, 0, 0,
        W2bf, 384, 0, 0, bias2,
        hnew_bf, HH, 0, 0, 384, h_bf);

    // 5. q12 = hnew @ [W_q1;W_q2]^T + bias (bf16 out, aliases Et region)
    gemm_mfma<0, 1><<<dim3(256, 2, 1), 256, 0, stream>>>(
        hnew_bf, nullptr, HH, 0, 0, 0, 0,
        Wq12, HH, 0, 0, biasq12,
        q12bf, 256, 0, 0, HH, nullptr);

    // 6. fused attention tail (mask, q0, scores, softmaxes, readout)
    k_tail<<<BB, 256, 0, stream>>>(hnew_bf, mask, q12bf, W_q0, b_q0, out);
}

// Round 7
// 217.842 us; speedup vs baseline: 1.4444x; 1.1463x over previous
//
#include <hip/hip_runtime.h>
#include <cstdint>
#include <cstddef>

// Problem constants (B=128, S=256, H=128, HEADS=8, STEP=1)
#define BB   128
#define SS   256
#define HH   128
#define NH   8
#define DKK  16

typedef unsigned short u16;
typedef __attribute__((ext_vector_type(8))) short   sh8;    // 8 bf16 = 4 VGPRs (MFMA A/B frag)
typedef __attribute__((ext_vector_type(4))) float   f32x4;  // MFMA C/D frag

__device__ __forceinline__ float sigmoidf_(float x) { return 1.f / (1.f + expf(-x)); }

__device__ __forceinline__ u16 f2bf(float x) {
    union { float f; unsigned int u; } v; v.f = x;
    unsigned int r = (v.u + 0x7fffu + ((v.u >> 16) & 1u)) >> 16;  // RNE (finite inputs)
    return (u16)r;
}
__device__ __forceinline__ float bf2f(u16 u) {
    union { unsigned int u; float f; } v; v.u = ((unsigned int)u) << 16;
    return v.f;
}
// unpack lo/hi bf16 of a packed u32 (no addressable locals)
__device__ __forceinline__ float bflo(unsigned u) {
    union { unsigned u; float f; } v; v.u = u << 16; return v.f;
}
__device__ __forceinline__ float bfhi(unsigned u) {
    union { unsigned u; float f; } v; v.u = u & 0xffff0000u; return v.f;
}

// ---------------------------------------------------------------------------
// bf16 MFMA GEMM, 128x128 tile, BK=32, 256 threads = 4 waves, each wave 64x64
// (4x4 grid of 16x16x32 MFMA).  B operands are B^T layout [N][K] bf16.
// Software-pipelined via NAMED register variables and straight-line macro
// loads — NO lambdas/arrays (round-5: lambda capture -> alloca -> 156 MB
// scratch traffic, 45->74 us regression).
// XMODE: 0 = bf16 [M][K] row-major
//        1 = fp32 [M][K] (convert to bf16 while staging)
//        2 = concat along K: bf16 Xa (ld ldx) for k<ksplit, bf16 Xc (ld ldx1) after
// OMODE: 1 = bf16 row-major
//        2 = bf16 TRANSPOSED (Out[col*ldo + row], packed ushort4 per C-quad)
//        3 = fused GRU gate epilogue, LDS-gather (W2 cols gate-interleaved,
//            col=4c+g, g: 0=r 1=i 2=n 3=hn); hnew = h - sig(gi)*(h -
//            tanh(i_n + sig(gr)*h_n)); h read from bf16 hid; coalesced stores.
// Batch (grid.z): z -> zb=z>>1, zh=z&1; element offsets = zb*s?b + zh*s?h.
// All dims are exact multiples of tile sizes for every call — no bounds checks.
// ---------------------------------------------------------------------------
#define BKk 32
#define PK  40   // LDS K pitch in halves (32 + 8): conflict-free frag reads

template<int XMODE, int OMODE>
__global__ __launch_bounds__(256) void gemm_mfma(
    const void* __restrict__ Xa, const void* __restrict__ Xc, int ldx, int ldx1, int ksplit,
    long long sXb, long long sXh,
    const u16* __restrict__ Bw, int ldb, long long sBb, long long sBh,
    const float* __restrict__ bias,
    void* __restrict__ Out, long long ldo, long long sOb, long long sOh,
    int K, const u16* __restrict__ hid)
{
    __shared__ __align__(16) char smem[2 * 128 * PK * 2];  // 20480 B
    u16* As = (u16*)smem;
    u16* Bs = (u16*)(smem + 128 * PK * 2);

    const int t  = threadIdx.x;
    const int bm = blockIdx.x * 128;
    const int bn = blockIdx.y * 128;
    const long long zb = blockIdx.z >> 1, zh = blockIdx.z & 1;

    const u16* Bp = Bw + zb * sBb + zh * sBh;

    const int wave = t >> 6, lane = t & 63;
    const int wr = (wave >> 1) * 64, wc = (wave & 1) * 64;
    const int fm = lane & 15, fq = lane >> 4;

    f32x4 acc[4][4] = {};

    const int r0  = t >> 2, kk0 = (t & 3) * 8;  // bf16 staging: 8 halves (16B), 2 chunks
    const int r1  = t >> 3, kk1 = (t & 7) * 4;  // fp32 staging: 4 floats, 4 chunks

    // prefetch registers — named scalars only (keep them out of scratch!)
    uint4  px0, px1, pb0, pb1;
    float4 pf0, pf1, pf2, pf3;

#define LOADX(K0)                                                                    \
    if (XMODE == 1) {                                                                \
        const float* Xf_ = (const float*)Xa + zb * sXb + zh * sXh;                   \
        const float* xp_ = Xf_ + (long long)(bm + r1) * ldx + (K0) + kk1;            \
        pf0 = *(const float4*)(xp_);                                                 \
        pf1 = *(const float4*)(xp_ + 32LL * ldx);                                    \
        pf2 = *(const float4*)(xp_ + 64LL * ldx);                                    \
        pf3 = *(const float4*)(xp_ + 96LL * ldx);                                    \
    } else if (XMODE == 2 && (K0) >= ksplit) {                                       \
        const u16* xp_ = (const u16*)Xc + (long long)(bm + r0) * ldx1                \
                         + ((K0) - ksplit) + kk0;                                    \
        px0 = *(const uint4*)(xp_);                                                  \
        px1 = *(const uint4*)(xp_ + 64LL * ldx1);                                    \
    } else {                                                                         \
        const u16* xp_ = (const u16*)Xa + (long long)(bm + r0) * ldx + (K0) + kk0;   \
        px0 = *(const uint4*)(xp_);                                                  \
        px1 = *(const uint4*)(xp_ + 64LL * ldx);                                     \
    }

#define LOADB(K0)                                                                    \
    {                                                                                \
        const u16* bp_ = Bp + (long long)(bn + r0) * ldb + (K0) + kk0;               \
        pb0 = *(const uint4*)(bp_);                                                  \
        pb1 = *(const uint4*)(bp_ + 64LL * ldb);                                     \
    }

    LOADX(0)
    LOADB(0)

    for (int k0 = 0; k0 < K; k0 += BKk) {
        // ---- commit prefetched tile to LDS ----
        if (XMODE == 1) {
            ushort4 w0 = { f2bf(pf0.x), f2bf(pf0.y), f2bf(pf0.z), f2bf(pf0.w) };
            ushort4 w1 = { f2bf(pf1.x), f2bf(pf1.y), f2bf(pf1.z), f2bf(pf1.w) };
            ushort4 w2 = { f2bf(pf2.x), f2bf(pf2.y), f2bf(pf2.z), f2bf(pf2.w) };
            ushort4 w3 = { f2bf(pf3.x), f2bf(pf3.y), f2bf(pf3.z), f2bf(pf3.w) };
            *(ushort4*)&As[(r1     ) * PK + kk1] = w0;
            *(ushort4*)&As[(r1 + 32) * PK + kk1] = w1;
            *(ushort4*)&As[(r1 + 64) * PK + kk1] = w2;
            *(ushort4*)&As[(r1 + 96) * PK + kk1] = w3;
        } else {
            *(uint4*)&As[(r0     ) * PK + kk0] = px0;
            *(uint4*)&As[(r0 + 64) * PK + kk0] = px1;
        }
        *(uint4*)&Bs[(r0     ) * PK + kk0] = pb0;
        *(uint4*)&Bs[(r0 + 64) * PK + kk0] = pb1;
        __syncthreads();

        // ---- issue next-tile loads (hide HBM latency behind frag+MFMA) ----
        if (k0 + BKk < K) {
            LOADX(k0 + BKk)
            LOADB(k0 + BKk)
        }

        sh8 af[4], bfr[4];
        #pragma unroll
        for (int i = 0; i < 4; i++) af[i]  = *(const sh8*)&As[(wr + i * 16 + fm) * PK + fq * 8];
        #pragma unroll
        for (int j = 0; j < 4; j++) bfr[j] = *(const sh8*)&Bs[(wc + j * 16 + fm) * PK + fq * 8];
        #pragma unroll
        for (int i = 0; i < 4; i++)
            #pragma unroll
            for (int j = 0; j < 4; j++)
                acc[i][j] = __builtin_amdgcn_mfma_f32_16x16x32_bf16(af[i], bfr[j], acc[i][j], 0, 0, 0);
        __syncthreads();
    }
#undef LOADX
#undef LOADB

    if (OMODE != 3) {
        // ---- epilogue: C layout col=lane&15, row=(lane>>4)*4+reg ----
        #pragma unroll
        for (int j = 0; j < 4; j++) {
            const int col = bn + wc + j * 16 + fm;
            const float bj = bias ? bias[col] : 0.f;
            #pragma unroll
            for (int i = 0; i < 4; i++) {
                const int row0 = bm + wr + i * 16 + fq * 4;
                if (OMODE == 1) {
                    u16* O = (u16*)Out + zb * sOb + zh * sOh;
                    #pragma unroll
                    for (int r = 0; r < 4; r++)
                        O[(long long)(row0 + r) * ldo + col] = f2bf(acc[i][j][r] + bj);
                } else {  // OMODE == 2
                    u16* O = (u16*)Out + zb * sOb + zh * sOh;
                    ushort4 w = { f2bf(acc[i][j][0] + bj), f2bf(acc[i][j][1] + bj),
                                  f2bf(acc[i][j][2] + bj), f2bf(acc[i][j][3] + bj) };
                    *(ushort4*)&O[(long long)col * ldo + row0] = w;  // 4 consecutive rows
                }
            }
        }
    } else {
        // ---- OMODE == 3: fused GRU epilogue, LDS-gather ----
        float* g4s = (float*)smem;       // [32][132] fp32 = 16896 B (reuses As/Bs)
        const int chbase = bn >> 2;      // global channel base for this block
        const int s_t = t >> 3;          // 0..31 slab row
        const int cq  = t & 7;           // 0..7 channel quad
        u16* O = (u16*)Out;
        const int sbase = (wr ? 16 : 0) + fq * 4;
        #pragma unroll
        for (int i = 0; i < 4; i++) {
            // scatter acc+bias into LDS (rows of both wave halves -> 32 slab rows)
            #pragma unroll
            for (int j = 0; j < 4; j++) {
                const int q = wc + j * 16 + fm;
                const float bj = bias[bn + q];
                #pragma unroll
                for (int r = 0; r < 4; r++)
                    g4s[(sbase + r) * 132 + q] = acc[i][j][r] + bj;
            }
            __syncthreads();
            // gather: 1 row x 4 channels per thread, contiguous b128 reads
            {
                const int grow = bm + i * 16 + (s_t < 16 ? s_t : s_t + 48);
                const ushort4 hv = *(const ushort4*)&hid[(long long)grow * HH + chbase + 4 * cq];
                const float hvv[4] = { bf2f(hv.x), bf2f(hv.y), bf2f(hv.z), bf2f(hv.w) };
                ushort4 w;
                u16* wp = (u16*)&w;
                #pragma unroll
                for (int m = 0; m < 4; m++) {
                    f32x4 gv = *(const f32x4*)&g4s[s_t * 132 + 16 * cq + 4 * m];
                    float rg = sigmoidf_(gv[0]);
                    float ig = sigmoidf_(gv[1]);
                    float ng = tanhf(gv[2] + rg * gv[3]);
                    wp[m] = f2bf(hvv[m] - ig * (hvv[m] - ng));
                }
                *(ushort4*)&O[(long long)grow * ldo + chbase + 4 * cq] = w;
            }
            __syncthreads();
        }
    }
}

// ---------------------------------------------------------------------------
// Weight prep + hidden cast (one kernel, grid 4096x256).
//   h_bf = bf16(hidden)  (1048576 float4s)
//   W2bf [512x384], GATE-INTERLEAVED rows: np = 4c+g, g: 0=r 1=i 2=n 3=hn.
//   bias2[np] = gate bias + fold of (b_iah|b_oah) through w_ih (linear terms).
//   Wcat [256x128] = [W_ein; W_eout], biascat = [b_ein|b_eout]
//   Wq12 [256x128] = [W_q1; W_q2],    biasq12 = [b_q1|b_q2]
// ---------------------------------------------------------------------------
__global__ __launch_bounds__(256) void k_prepw(
    const float* __restrict__ hidden, u16* __restrict__ h_bf,
    const float* __restrict__ w_ih, const float* __restrict__ w_hh,
    const float* __restrict__ b_ih, const float* __restrict__ b_hh,
    const float* __restrict__ b_iah, const float* __restrict__ b_oah,
    const float* __restrict__ W_ein, const float* __restrict__ b_ein,
    const float* __restrict__ W_eout, const float* __restrict__ b_eout,
    const float* __restrict__ W_q1, const float* __restrict__ b_q1,
    const float* __restrict__ W_q2, const float* __restrict__ b_q2,
    u16* __restrict__ W2bf, float* __restrict__ bias2,
    u16* __restrict__ Wcat, float* __restrict__ biascat,
    u16* __restrict__ Wq12, float* __restrict__ biasq12)
{
    int idx = blockIdx.x * 256 + threadIdx.x;  // 0 .. 1048575
    {   // hidden -> bf16, 4 elems/thread
        float4 v = ((const float4*)hidden)[idx];
        ushort4 w = { f2bf(v.x), f2bf(v.y), f2bf(v.z), f2bf(v.w) };
        ((ushort4*)h_bf)[idx] = w;
    }
    if (idx < 512 * 384) {
        int np = idx / 384, kk = idx % 384;
        int c = np >> 2, g = np & 3;
        float v;
        if (g < 2)       v = (kk < 256) ? w_ih[(g * 128 + c) * 256 + kk]
                                        : w_hh[(g * 128 + c) * 128 + kk - 256];
        else if (g == 2) v = (kk < 256) ? w_ih[(256 + c) * 256 + kk] : 0.f;
        else             v = (kk < 256) ? 0.f : w_hh[(256 + c) * 128 + kk - 256];
        W2bf[idx] = f2bf(v);
    }
    if (idx < 256 * 128) {
        int n = idx >> 7, k = idx & 127;
        Wcat[idx] = f2bf(n < 128 ? W_ein[n * 128 + k] : W_eout[(n - 128) * 128 + k]);
        Wq12[idx] = f2bf(n < 128 ? W_q1[n * 128 + k]  : W_q2[(n - 128) * 128 + k]);
    }
    if (idx < 512) {
        int np = idx, c = np >> 2, g = np & 3;
        float s;
        if (g < 2)       s = b_ih[g * 128 + c] + b_hh[g * 128 + c];
        else if (g == 2) s = b_ih[256 + c];
        else             s = b_hh[256 + c];
        if (g < 3) {
            int n = (g < 2) ? g * 128 + c : 256 + c;
            for (int k = 0; k < 128; k++)
                s += w_ih[n * 256 + k] * b_iah[k] + w_ih[n * 256 + 128 + k] * b_oah[k];
        }
        bias2[np] = s;
    }
    if (idx < 256) {
        biascat[idx] = idx < 128 ? b_ein[idx] : b_eout[idx - 128];
        biasq12[idx] = idx < 128 ? b_q1[idx]  : b_q2[idx - 128];
    }
}

// ---------------------------------------------------------------------------
// Fused attention tail v2: one block per batch b, 1024 threads (16 waves) for
// latency hiding (round-6 k_tail was 42 us at 4.7% occupancy / 2.7% VALUBusy).
// mask-sum -> last idx -> q0 -> sigmoid scores -> softmax_j -> softmax_h ->
// weighted q2 readout, out[b] scaled by nvalid.  q12 is bf16 [32768][256]
// (cols 0:128 = q1, 128:256 = q2).
// ---------------------------------------------------------------------------
__global__ __launch_bounds__(1024) void k_tail(
    const u16* __restrict__ hnew_bf, const int* __restrict__ mask,
    const u16* __restrict__ q12, const float* __restrict__ Wq0,
    const float* __restrict__ bq0, float* __restrict__ out)
{
    const int b = blockIdx.x, t = threadIdx.x;
    __shared__ float red[1024];
    __shared__ float hs[HH];
    __shared__ float q0s[HH];
    __shared__ float p_s[NH][SS];
    __shared__ float w_s[NH][SS];
    __shared__ int s_nv;

    // ---- mask sum / last index (threads 0..255 active in tree) ----
    if (t < 256) red[t] = (float)mask[b * SS + t];
    __syncthreads();
    for (int off = 128; off > 0; off >>= 1) {
        if (t < off) red[t] += red[t + off];
        __syncthreads();
    }
    if (t == 0) s_nv = (int)red[0];
    __syncthreads();
    const int nv = s_nv;
    const int last = (nv - 1) & (SS - 1);

    if (t < HH) hs[t] = bf2f(hnew_bf[((size_t)b * SS + last) * HH + t]);
    __syncthreads();

    // ---- q0 = h_last @ Wq0^T + bq0: n = t&127, K split 8 ways ----
    {
        const int n = t & 127, kh = t >> 7;  // kh 0..7, 16 k each
        const float* w = Wq0 + (size_t)n * HH + kh * 16;
        const float* h = hs + kh * 16;
        float s = 0.f;
        #pragma unroll
        for (int k = 0; k < 16; k++) s += h[k] * w[k];
        red[t] = s;
    }
    __syncthreads();
    if (t < HH) {
        float s = bq0[t];
        #pragma unroll
        for (int kh = 0; kh < 8; kh++) s += red[kh * 128 + t];
        q0s[t] = s;
    }
    __syncthreads();

    // ---- scores: j = t>>2 (256), q = t&3; thread computes heads 2q, 2q+1 ----
    {
        const int j = t >> 2, q = t & 3;
        const u16* q1r = q12 + ((size_t)b * SS + j) * 256 + q * 32;
        uint4 va = *(const uint4*)(q1r);
        uint4 vb = *(const uint4*)(q1r + 8);
        uint4 vc = *(const uint4*)(q1r + 16);
        uint4 vd = *(const uint4*)(q1r + 24);
        const float* qa = q0s + q * 32;
        float s0 = qa[0]  * bflo(va.x) + qa[1]  * bfhi(va.x)
                 + qa[2]  * bflo(va.y) + qa[3]  * bfhi(va.y)
                 + qa[4]  * bflo(va.z) + qa[5]  * bfhi(va.z)
                 + qa[6]  * bflo(va.w) + qa[7]  * bfhi(va.w)
                 + qa[8]  * bflo(vb.x) + qa[9]  * bfhi(vb.x)
                 + qa[10] * bflo(vb.y) + qa[11] * bfhi(vb.y)
                 + qa[12] * bflo(vb.z) + qa[13] * bfhi(vb.z)
                 + qa[14] * bflo(vb.w) + qa[15] * bfhi(vb.w);
        float s1 = qa[16] * bflo(vc.x) + qa[17] * bfhi(vc.x)
                 + qa[18] * bflo(vc.y) + qa[19] * bfhi(vc.y)
                 + qa[20] * bflo(vc.z) + qa[21] * bfhi(vc.z)
                 + qa[22] * bflo(vc.w) + qa[23] * bfhi(vc.w)
                 + qa[24] * bflo(vd.x) + qa[25] * bfhi(vd.x)
                 + qa[26] * bflo(vd.y) + qa[27] * bfhi(vd.y)
                 + qa[28] * bflo(vd.z) + qa[29] * bfhi(vd.z)
                 + qa[30] * bflo(vd.w) + qa[31] * bfhi(vd.w);
        p_s[2 * q][j]     = sigmoidf_(s0);
        p_s[2 * q + 1][j] = sigmoidf_(s1);
    }
    __syncthreads();

    // ---- softmax over j per head (threads 0..255: 32 lanes/head, 8 vals) ----
    if (t < 256) {
        const int h = t >> 5, l = t & 31;
        float v[8], m = -1e30f;
        #pragma unroll
        for (int u = 0; u < 8; u++) { v[u] = p_s[h][l * 8 + u]; m = fmaxf(m, v[u]); }
        #pragma unroll
        for (int msk = 1; msk < 32; msk <<= 1) m = fmaxf(m, __shfl_xor(m, msk, 32));
        float sum = 0.f;
        #pragma unroll
        for (int u = 0; u < 8; u++) { v[u] = expf(v[u] - m); sum += v[u]; }
        #pragma unroll
        for (int msk = 1; msk < 32; msk <<= 1) sum += __shfl_xor(sum, msk, 32);
        const float inv = 1.f / sum;
        #pragma unroll
        for (int u = 0; u < 8; u++) p_s[h][l * 8 + u] = v[u] * inv;
    }
    __syncthreads();

    // ---- head softmax per j (threads 0..255) ----
    if (t < 256) {
        float e[NH], den = 0.f;
        #pragma unroll
        for (int h = 0; h < NH; h++) { e[h] = expf(2.f * p_s[h][t]); den += e[h]; }
        const float inv = 1.f / den;
        #pragma unroll
        for (int h = 0; h < NH; h++) w_s[h][t] = e[h] * inv;
    }
    __syncthreads();

    // ---- readout: col = t&127, j split 8 ways; LDS cross-reduce ----
    {
        const int col = t & 127, jq = t >> 7;
        const int h = col >> 4;
        const u16* q2b = q12 + (size_t)b * SS * 256 + 128 + col;
        float acc = 0.f;
        #pragma unroll 4
        for (int j = jq * 32; j < jq * 32 + 32; j++)
            acc += w_s[h][j] * bf2f(q2b[(size_t)j * 256]);
        red[t] = acc;
    }
    __syncthreads();
    if (t < HH) {
        float s = 0.f;
        #pragma unroll
        for (int jq = 0; jq < 8; jq++) s += red[jq * 128 + t];
        out[(size_t)b * HH + t] = s * (float)nv;
    }
}

// ---------------------------------------------------------------------------
extern "C" void kernel_launch(void* const* d_in, const int* in_sizes, int n_in,
                              void* d_out, int out_size, void* d_ws, size_t ws_size,
                              hipStream_t stream)
{
    const float* A      = (const float*)d_in[0];
    const float* hidden = (const float*)d_in[1];
    const int*   mask   = (const int*)d_in[2];
    const float* w_ih   = (const float*)d_in[3];
    const float* w_hh   = (const float*)d_in[4];
    const float* b_ih   = (const float*)d_in[5];
    const float* b_hh   = (const float*)d_in[6];
    const float* b_iah  = (const float*)d_in[7];
    const float* b_oah  = (const float*)d_in[8];
    const float* W_ein  = (const float*)d_in[9];
    const float* b_ein  = (const float*)d_in[10];
    const float* W_eout = (const float*)d_in[11];
    const float* b_eout = (const float*)d_in[12];
    const float* W_q0   = (const float*)d_in[13];
    const float* b_q0   = (const float*)d_in[14];
    const float* W_q1   = (const float*)d_in[15];
    const float* b_q1   = (const float*)d_in[16];
    const float* W_q2   = (const float*)d_in[17];
    const float* b_q2   = (const float*)d_in[18];
    float* out = (float*)d_out;
    char* ws = (char*)d_ws;

    // --- workspace layout (bytes) ---
    u16*   Et      = (u16*)(ws + 0);             // [256][32768] bf16 (E transposed)
    u16*   Mbuf    = (u16*)(ws + 16777216);      // [32768][256] bf16 (msg_in|msg_out)
    u16*   q12bf   = (u16*)(ws + 0);             // [32768][256] bf16 — aliases Et (dead)
    u16*   hnew_bf = (u16*)(ws + 33554432);      // [32768][128] bf16
    u16*   h_bf    = (u16*)(ws + 41943040);      // [32768][128] bf16
    u16*   W2bf    = (u16*)(ws + 50331648);      // [512][384]
    u16*   Wcat    = (u16*)(ws + 50724864);      // [256][128]
    u16*   Wq12    = (u16*)(ws + 50790400);      // [256][128]
    float* bias2   = (float*)(ws + 50855936);    // [512]
    float* biascat = (float*)(ws + 50857984);    // [256]
    float* biasq12 = (float*)(ws + 50859008);    // [256]

    // 1. weight prep + hidden cast
    k_prepw<<<4096, 256, 0, stream>>>(hidden, h_bf,
                                      w_ih, w_hh, b_ih, b_hh, b_iah, b_oah,
                                      W_ein, b_ein, W_eout, b_eout,
                                      W_q1, b_q1, W_q2, b_q2,
                                      W2bf, bias2, Wcat, biascat, Wq12, biasq12);

    // 2. E = h_bf @ [W_ein;W_eout]^T + bias, stored TRANSPOSED (Et[c][r])
    gemm_mfma<0, 2><<<dim3(256, 2, 1), 256, 0, stream>>>(
        h_bf, nullptr, HH, 0, 0, 0, 0,
        Wcat, HH, 0, 0, biascat,
        Et, 32768, 0, 0, HH, nullptr);

    // 3. msg: per (b,half): A-half[b] (fp32, ld 512) @ Et-slice^T -> Mbuf bf16
    gemm_mfma<1, 1><<<dim3(2, 1, 256), 256, 0, stream>>>(
        A, nullptr, 512, 0, 0, 131072LL, 256LL,
        Et, 32768, 256LL, 128LL * 32768LL, nullptr,
        Mbuf, 256, 65536LL, 128LL, SS, nullptr);

    // 4. gates = [Mbuf | h_bf] @ W2bf^T + bias2, fused GRU epilogue
    //    (LDS-gather) -> hnew bf16 directly
    gemm_mfma<2, 3><<<dim3(256, 4, 1), 256, 0, stream>>>(
        Mbuf, h_bf, 256, HH, 256, 0, 0,
        W2bf, 384, 0, 0, bias2,
        hnew_bf, HH, 0, 0, 384, h_bf);

    // 5. q12 = hnew @ [W_q1;W_q2]^T + bias (bf16 out, aliases Et region)
    gemm_mfma<0, 1><<<dim3(256, 2, 1), 256, 0, stream>>>(
        hnew_bf, nullptr, HH, 0, 0, 0, 0,
        Wq12, HH, 0, 0, biasq12,
        q12bf, 256, 0, 0, HH, nullptr);

    // 6. fused attention tail v2 (1024 threads/block)
    k_tail<<<BB, 1024, 0, stream>>>(hnew_bf, mask, q12bf, W_q0, b_q0, out);
}